// Round 5
// baseline (1255.098 us; speedup 1.0000x reference)
//
#include <hip/hip_runtime.h>

#define N_NODES 100000
#define N_EDGES 3200000
#define F_IN    512
#define HIDDEN  16
#define N_CLASS 10

// index load robust to int32/int64 (is32 nonzero => int32). Probe decides; both
// probe reads stay within the smaller (int32) buffer size.
__device__ __forceinline__ int load_idx(const void* ei, int is32, long long pos) {
    return is32 ? ((const int*)ei)[pos] : (int)((const long long*)ei)[pos];
}

__global__ void k_zero(float* __restrict__ p, int n) {
    int i = blockIdx.x * 256 + threadIdx.x;
    if (i < n) p[i] = 0.0f;
}
__global__ void k_fill1(float* __restrict__ p, int n) {
    int i = blockIdx.x * 256 + threadIdx.x;
    if (i < n) p[i] = 1.0f;
}

// int64 storage (values < 2^31) => all odd 32-bit words are 0; int32 => mostly nonzero.
__global__ void k_detect(const unsigned* __restrict__ ei, int* __restrict__ det) {
    int t = threadIdx.x;
    unsigned odd = 0;
    for (int i = t; i < 4096; i += 256) odd |= ei[2 * i + 1];   // reads 32KB, safe
    if (odd) atomicOr(&det[0], 1);
}

__global__ void k_deg(const void* __restrict__ ei, const int* __restrict__ det,
                      float* __restrict__ deg) {
    int e = blockIdx.x * 256 + threadIdx.x;
    if (e < N_EDGES) {
        int is32 = det[0];
        int d = load_idx(ei, is32, (long long)N_EDGES + e);
        atomicAdd(&deg[d], 1.0f);     // integer counts <= ~100: exact in fp32
    }
}

__global__ void k_dinv(float* __restrict__ deg) {
    int i = blockIdx.x * 256 + threadIdx.x;
    if (i < N_NODES) deg[i] = rsqrtf(deg[i]);
}

// W1 [512][16] fp32 -> Wt [16][512] fp32 (per-output-feature contiguous)
__global__ void k_wt(const float* __restrict__ W1, float* __restrict__ Wt) {
    int t = blockIdx.x * 256 + threadIdx.x;
    if (t < F_IN * HIDDEN) {
        int k = t >> 9;          // 0..15
        int j = t & (F_IN - 1);  // 0..511
        Wt[t] = W1[j * HIDDEN + k];
    }
}

// hw[N][16] = x @ W1, fp32. gid = row*16 + k; 16 lanes share one x row (L1 broadcast).
__global__ __launch_bounds__(256) void k_gemm1(const float* __restrict__ x,
                                               const float* __restrict__ Wt,
                                               float* __restrict__ hw) {
    int gid = blockIdx.x * 256 + threadIdx.x;
    int row = gid >> 4;
    int k   = gid & 15;
    if (row >= N_NODES) return;
    const float4* xr = (const float4*)(x + (size_t)row * F_IN);
    const float4* wr = (const float4*)(Wt + k * F_IN);
    float acc = 0.f;
#pragma unroll 8
    for (int c = 0; c < F_IN / 4; ++c) {
        float4 a = xr[c];
        float4 b = wr[c];
        acc += a.x * b.x + a.y * b.y + a.z * b.z + a.w * b.w;
    }
    hw[gid] = acc;
}

// layer-1 scatter: a1[dst][k] += hw[src][k] * norm  (16 lanes/edge)
__global__ void k_scatter1(const void* __restrict__ ei, const int* __restrict__ det,
                           const float* __restrict__ dinv, const float* __restrict__ hw,
                           float* __restrict__ a1) {
    int gid = blockIdx.x * 256 + threadIdx.x;
    int e = gid >> 4;
    int k = gid & 15;
    if (e >= N_EDGES) return;
    int is32 = det[0];
    int s = load_idx(ei, is32, e);
    int d = load_idx(ei, is32, (long long)N_EDGES + e);
    float nrm = dinv[s] * dinv[d];
    atomicAdd(&a1[d * HIDDEN + k], hw[s * HIDDEN + k] * nrm);
}

// self-loop + bias + ReLU + (16->10) transform
__global__ void k_mid(const float* __restrict__ a1, const float* __restrict__ hw,
                      const float* __restrict__ dinv, const float* __restrict__ b1,
                      const float* __restrict__ W2, float* __restrict__ t2) {
    int i = blockIdx.x * 256 + threadIdx.x;
    if (i >= N_NODES) return;
    float di = dinv[i];
    float d2 = di * di;
    float h[HIDDEN];
#pragma unroll
    for (int k = 0; k < HIDDEN; ++k) {
        float v = a1[i * HIDDEN + k] + hw[i * HIDDEN + k] * d2 + b1[k];
        h[k] = v > 0.f ? v : 0.f;
    }
#pragma unroll
    for (int c = 0; c < N_CLASS; ++c) {
        float acc = 0.f;
#pragma unroll
        for (int k = 0; k < HIDDEN; ++k) acc += h[k] * W2[k * N_CLASS + c];
        t2[i * N_CLASS + c] = acc;
    }
}

// layer-2 scatter: out32[dst][c] += t2[src][c] * norm  (16 lanes/edge, 10 active)
__global__ void k_scatter2(const void* __restrict__ ei, const int* __restrict__ det,
                           const float* __restrict__ dinv, const float* __restrict__ t2,
                           float* __restrict__ o32) {
    int gid = blockIdx.x * 256 + threadIdx.x;
    int e = gid >> 4;
    int k = gid & 15;
    if (e >= N_EDGES || k >= N_CLASS) return;
    int is32 = det[0];
    int s = load_idx(ei, is32, e);
    int d = load_idx(ei, is32, (long long)N_EDGES + e);
    float nrm = dinv[s] * dinv[d];
    atomicAdd(&o32[d * N_CLASS + k], t2[s * N_CLASS + k] * nrm);
}

// self-loop + bias, fp32 output
__global__ void k_final(const float* __restrict__ o32, const float* __restrict__ t2,
                        const float* __restrict__ dinv, const float* __restrict__ b2,
                        float* __restrict__ out) {
    int gid = blockIdx.x * 256 + threadIdx.x;
    if (gid >= N_NODES * N_CLASS) return;
    int i = gid / N_CLASS;
    int c = gid - i * N_CLASS;
    float di = dinv[i];
    out[gid] = o32[gid] + t2[gid] * di * di + b2[c];
}

extern "C" void kernel_launch(void* const* d_in, const int* in_sizes, int n_in,
                              void* d_out, int out_size, void* d_ws, size_t ws_size,
                              hipStream_t stream) {
    const float* x  = (const float*)d_in[0];   // fp32 [N,512] (bf16-quantized values)
    const void*  ei = d_in[1];                 // int32 (probed; int64 also handled)
    const float* W1 = (const float*)d_in[2];   // fp32 [512,16]
    const float* b1 = (const float*)d_in[3];   // fp32 [16]
    const float* W2 = (const float*)d_in[4];   // fp32 [16,10]
    const float* b2 = (const float*)d_in[5];   // fp32 [10]
    float* out = (float*)d_out;                // fp32 [N,10]
    float* ws  = (float*)d_ws;

    // ws layout (4-byte units)
    float* dinv = ws;                   // 100,000 (pad to 100,096)
    float* hw   = ws + 100096;          // 1,600,000
    float* a1   = ws + 1700096;         // 1,600,000
    float* t2   = ws + 3300096;         // 1,000,000
    float* o32  = ws + 4300096;         // 1,000,000
    float* Wt   = ws + 5300096;         // 8,192
    int*   det  = (int*)(ws + 5308288); // 1 int
    // total ~5.31M words ≈ 21.3 MB

    k_zero  <<<(N_NODES * HIDDEN + 255) / 256, 256, 0, stream>>>(a1, N_NODES * HIDDEN);
    k_zero  <<<(N_NODES * N_CLASS + 255) / 256, 256, 0, stream>>>(o32, N_NODES * N_CLASS);
    k_zero  <<<1, 64, 0, stream>>>((float*)det, 1);
    k_fill1 <<<(N_NODES + 255) / 256, 256, 0, stream>>>(dinv, N_NODES);  // deg starts at 1

    k_detect<<<1, 256, 0, stream>>>((const unsigned*)ei, det);
    k_deg   <<<N_EDGES / 256, 256, 0, stream>>>(ei, det, dinv);
    k_dinv  <<<(N_NODES + 255) / 256, 256, 0, stream>>>(dinv);

    k_wt    <<<(F_IN * HIDDEN) / 256, 256, 0, stream>>>(W1, Wt);
    k_gemm1 <<<(N_NODES * 16) / 256, 256, 0, stream>>>(x, Wt, hw);

    k_scatter1<<<(N_EDGES * 16) / 256, 256, 0, stream>>>(ei, det, dinv, hw, a1);
    k_mid     <<<(N_NODES + 255) / 256, 256, 0, stream>>>(a1, hw, dinv, b1, W2, t2);
    k_scatter2<<<(N_EDGES * 16) / 256, 256, 0, stream>>>(ei, det, dinv, t2, o32);
    k_final   <<<(N_NODES * N_CLASS + 255) / 256, 256, 0, stream>>>(o32, t2, dinv, b2, out);
}

// Round 6
// 960.185 us; speedup vs baseline: 1.3071x; 1.3071x over previous
//
#include <hip/hip_runtime.h>

#define N_NODES 100000
#define N_EDGES 3200000
#define F_IN    512
#define HIDDEN  16
#define N_CLASS 10

#define TILE_R  256
#define KC      64
#define XSTRIDE 68   // padded LDS stride (floats); %4==0 for b128, %32==4 for bank spread

// index load robust to int32/int64 (is32 nonzero => int32)
__device__ __forceinline__ int load_idx(const void* ei, int is32, long long pos) {
    return is32 ? ((const int*)ei)[pos] : (int)((const long long*)ei)[pos];
}

__global__ void k_zero(float* __restrict__ p, int n) {
    int i = blockIdx.x * 256 + threadIdx.x;
    if (i < n) p[i] = 0.0f;
}
__global__ void k_fill1(float* __restrict__ p, int n) {
    int i = blockIdx.x * 256 + threadIdx.x;
    if (i < n) p[i] = 1.0f;
}

// int64 storage (values < 2^31) => all odd 32-bit words are 0; int32 => mostly nonzero.
__global__ void k_detect(const unsigned* __restrict__ ei, int* __restrict__ det) {
    int t = threadIdx.x;
    unsigned odd = 0;
    for (int i = t; i < 4096; i += 256) odd |= ei[2 * i + 1];   // 32KB read, safe either way
    if (odd) atomicOr(&det[0], 1);
}

__global__ void k_deg(const void* __restrict__ ei, const int* __restrict__ det,
                      float* __restrict__ deg) {
    int e = blockIdx.x * 256 + threadIdx.x;
    if (e < N_EDGES) {
        int is32 = det[0];
        int d = load_idx(ei, is32, (long long)N_EDGES + e);
        atomicAdd(&deg[d], 1.0f);     // integer counts: exact in fp32
    }
}

__global__ void k_dinv(float* __restrict__ deg) {
    int i = blockIdx.x * 256 + threadIdx.x;
    if (i < N_NODES) deg[i] = rsqrtf(deg[i]);
}

// W1 [512][16] -> Wt [16][512] (per-output-feature contiguous rows)
__global__ void k_wt(const float* __restrict__ W1, float* __restrict__ Wt) {
    int t = blockIdx.x * 256 + threadIdx.x;
    if (t < F_IN * HIDDEN) {
        int k = t >> 9;
        int j = t & (F_IN - 1);
        Wt[t] = W1[j * HIDDEN + k];
    }
}

// hw[N][16] = x @ W1. LDS-tiled: 256-row tile, K chunks of 64.
// Wave w owns output cols 4w..4w+3 (wave-uniform -> scalar W loads).
// Lane l owns rows l, l+64, l+128, l+192 of the tile (4x4 register tile).
__global__ __launch_bounds__(256) void k_gemm1(const float* __restrict__ x,
                                               const float* __restrict__ Wt,
                                               float* __restrict__ hw) {
    __shared__ float sX[TILE_R * XSTRIDE];
    int t = threadIdx.x;
    int lane = t & 63;
    int rowbase = blockIdx.x * TILE_R;
    int kbase = __builtin_amdgcn_readfirstlane((t >> 6) << 2);   // 0,4,8,12
    const float* wk = Wt + kbase * F_IN;

    float acc[4][4] = {};
#pragma unroll 1
    for (int ch = 0; ch < F_IN / KC; ++ch) {
        __syncthreads();   // protect previous chunk's reads
        // stage x[rowbase..rowbase+255][ch*64..ch*64+63] -> sX, coalesced
#pragma unroll
        for (int i = 0; i < 16; ++i) {
            int f   = i * 256 + t;       // 0..4095
            int row = f >> 4;            // 0..255
            int c4  = f & 15;            // float4 index within row-chunk
            int grow = rowbase + row;
            float4 v = make_float4(0.f, 0.f, 0.f, 0.f);
            if (grow < N_NODES)
                v = ((const float4*)(x + (size_t)grow * F_IN + ch * KC))[c4];
            *((float4*)&sX[row * XSTRIDE + c4 * 4]) = v;
        }
        __syncthreads();
        // compute: per 4-j step: 4 ds_read_b128 (x) + 4 scalar float4 (W) -> 64 FMA
#pragma unroll
        for (int js = 0; js < KC; js += 4) {
            float4 xv[4];
#pragma unroll
            for (int r = 0; r < 4; ++r)
                xv[r] = *((const float4*)&sX[(lane + 64 * r) * XSTRIDE + js]);
#pragma unroll
            for (int kk = 0; kk < 4; ++kk) {
                const float* wp = wk + kk * F_IN + ch * KC + js;
                float w0 = wp[0], w1 = wp[1], w2 = wp[2], w3 = wp[3];
#pragma unroll
                for (int r = 0; r < 4; ++r)
                    acc[r][kk] += xv[r].x * w0 + xv[r].y * w1
                                + xv[r].z * w2 + xv[r].w * w3;
            }
        }
    }
#pragma unroll
    for (int r = 0; r < 4; ++r) {
        int grow = rowbase + lane + 64 * r;
        if (grow < N_NODES)
            *((float4*)&hw[(size_t)grow * HIDDEN + kbase]) =
                make_float4(acc[r][0], acc[r][1], acc[r][2], acc[r][3]);
    }
}

// layer-1 scatter: a1[dst][k] += hw[src][k] * norm  (16 lanes/edge)
__global__ void k_scatter1(const void* __restrict__ ei, const int* __restrict__ det,
                           const float* __restrict__ dinv, const float* __restrict__ hw,
                           float* __restrict__ a1) {
    int gid = blockIdx.x * 256 + threadIdx.x;
    int e = gid >> 4;
    int k = gid & 15;
    if (e >= N_EDGES) return;
    int is32 = det[0];
    int s = load_idx(ei, is32, e);
    int d = load_idx(ei, is32, (long long)N_EDGES + e);
    float nrm = dinv[s] * dinv[d];
    atomicAdd(&a1[d * HIDDEN + k], hw[s * HIDDEN + k] * nrm);
}

// self-loop + bias + ReLU + (16->10) transform
__global__ void k_mid(const float* __restrict__ a1, const float* __restrict__ hw,
                      const float* __restrict__ dinv, const float* __restrict__ b1,
                      const float* __restrict__ W2, float* __restrict__ t2) {
    int i = blockIdx.x * 256 + threadIdx.x;
    if (i >= N_NODES) return;
    float di = dinv[i];
    float d2 = di * di;
    float h[HIDDEN];
#pragma unroll
    for (int k = 0; k < HIDDEN; ++k) {
        float v = a1[i * HIDDEN + k] + hw[i * HIDDEN + k] * d2 + b1[k];
        h[k] = v > 0.f ? v : 0.f;
    }
#pragma unroll
    for (int c = 0; c < N_CLASS; ++c) {
        float acc = 0.f;
#pragma unroll
        for (int k = 0; k < HIDDEN; ++k) acc += h[k] * W2[k * N_CLASS + c];
        t2[i * N_CLASS + c] = acc;
    }
}

// layer-2 scatter: o32[dst][c] += t2[src][c] * norm  (16 lanes/edge, 10 active)
__global__ void k_scatter2(const void* __restrict__ ei, const int* __restrict__ det,
                           const float* __restrict__ dinv, const float* __restrict__ t2,
                           float* __restrict__ o32) {
    int gid = blockIdx.x * 256 + threadIdx.x;
    int e = gid >> 4;
    int k = gid & 15;
    if (e >= N_EDGES || k >= N_CLASS) return;
    int is32 = det[0];
    int s = load_idx(ei, is32, e);
    int d = load_idx(ei, is32, (long long)N_EDGES + e);
    float nrm = dinv[s] * dinv[d];
    atomicAdd(&o32[d * N_CLASS + k], t2[s * N_CLASS + k] * nrm);
}

// self-loop + bias, fp32 output
__global__ void k_final(const float* __restrict__ o32, const float* __restrict__ t2,
                        const float* __restrict__ dinv, const float* __restrict__ b2,
                        float* __restrict__ out) {
    int gid = blockIdx.x * 256 + threadIdx.x;
    if (gid >= N_NODES * N_CLASS) return;
    int i = gid / N_CLASS;
    int c = gid - i * N_CLASS;
    float di = dinv[i];
    out[gid] = o32[gid] + t2[gid] * di * di + b2[c];
}

extern "C" void kernel_launch(void* const* d_in, const int* in_sizes, int n_in,
                              void* d_out, int out_size, void* d_ws, size_t ws_size,
                              hipStream_t stream) {
    const float* x  = (const float*)d_in[0];   // fp32 [N,512]
    const void*  ei = d_in[1];                 // int32 (probed; int64 handled)
    const float* W1 = (const float*)d_in[2];   // fp32 [512,16]
    const float* b1 = (const float*)d_in[3];   // fp32 [16]
    const float* W2 = (const float*)d_in[4];   // fp32 [16,10]
    const float* b2 = (const float*)d_in[5];   // fp32 [10]
    float* out = (float*)d_out;                // fp32 [N,10]
    float* ws  = (float*)d_ws;

    // ws layout (4-byte units)
    float* dinv = ws;                   // 100,000 (pad to 100,096)
    float* hw   = ws + 100096;          // 1,600,000
    float* a1   = ws + 1700096;         // 1,600,000
    float* t2   = ws + 3300096;         // 1,000,000
    float* o32  = ws + 4300096;         // 1,000,000
    float* Wt   = ws + 5300096;         // 8,192
    int*   det  = (int*)(ws + 5308288); // 1 int

    k_zero  <<<(N_NODES * HIDDEN + 255) / 256, 256, 0, stream>>>(a1, N_NODES * HIDDEN);
    k_zero  <<<(N_NODES * N_CLASS + 255) / 256, 256, 0, stream>>>(o32, N_NODES * N_CLASS);
    k_zero  <<<1, 64, 0, stream>>>((float*)det, 1);
    k_fill1 <<<(N_NODES + 255) / 256, 256, 0, stream>>>(dinv, N_NODES);  // deg starts at 1

    k_detect<<<1, 256, 0, stream>>>((const unsigned*)ei, det);
    k_deg   <<<N_EDGES / 256, 256, 0, stream>>>(ei, det, dinv);
    k_dinv  <<<(N_NODES + 255) / 256, 256, 0, stream>>>(dinv);

    k_wt    <<<(F_IN * HIDDEN) / 256, 256, 0, stream>>>(W1, Wt);
    k_gemm1 <<<(N_NODES + TILE_R - 1) / TILE_R, 256, 0, stream>>>(x, Wt, hw);

    k_scatter1<<<(N_EDGES * 16) / 256, 256, 0, stream>>>(ei, det, dinv, hw, a1);
    k_mid     <<<(N_NODES + 255) / 256, 256, 0, stream>>>(a1, hw, dinv, b1, W2, t2);
    k_scatter2<<<(N_EDGES * 16) / 256, 256, 0, stream>>>(ei, det, dinv, t2, o32);
    k_final   <<<(N_NODES * N_CLASS + 255) / 256, 256, 0, stream>>>(o32, t2, dinv, b2, out);
}